// Round 1
// baseline (87.001 us; speedup 1.0000x reference)
//
#include <hip/hip_runtime.h>
#include <math.h>

// MultiHeadAttentionQuantum: analytic collapse of the 8-qubit circuit.
//   angles[t][n] = dot(x[t], w_q[n]) + q_params[n]
//   c[n] = cos(angles[n])
//   z[0] = c1*c2*...*c7 ; z[w] = c0*...*cw (w>=1)   (Heisenberg CNOT-ring push-through)
//   out[t][e] = sum_n z[n] * w_out[e][n]
// Memory-bound: ~201 MB HBM traffic -> ~32 us floor.

constexpr int E  = 768;
constexpr int NW = 8;
constexpr int BLOCK = 256;           // 4 waves
constexpr int TOK_PER_BLOCK = 64;    // 16 tokens per wave, 4 iters of 4
constexpr int GRID = (16 * 2048) / TOK_PER_BLOCK;  // 512

__device__ __forceinline__ float dot12(const float4& a0, const float4& a1, const float4& a2,
                                       const float4& b0, const float4& b1, const float4& b2) {
    return a0.x*b0.x + a0.y*b0.y + a0.z*b0.z + a0.w*b0.w
         + a1.x*b1.x + a1.y*b1.y + a1.z*b1.z + a1.w*b1.w
         + a2.x*b2.x + a2.y*b2.y + a2.z*b2.z + a2.w*b2.w;
}

__global__ __launch_bounds__(BLOCK, 2)
void mhaq_kernel(const float* __restrict__ x,
                 const float* __restrict__ w_q,
                 const float* __restrict__ w_out,
                 const float* __restrict__ q_params,
                 float* __restrict__ out)
{
    __shared__ float wq_lds[NW][E];   // 24 KB, w_q as-is [n][e]
    __shared__ float wt_lds[NW][E];   // 24 KB, w_out TRANSPOSED [n][e] (conflict-free b128 reads)

    const int tid = threadIdx.x;

    // ---- stage w_q (straight copy, 1536 float4) ----
    {
        const float4* src = reinterpret_cast<const float4*>(w_q);
        float4* dst = reinterpret_cast<float4*>(&wq_lds[0][0]);
        #pragma unroll
        for (int r = 0; r < (NW * E / 4) / BLOCK; ++r)
            dst[tid + r * BLOCK] = src[tid + r * BLOCK];
    }
    // ---- stage w_out transposed: w_out[e][n] -> wt_lds[n][e] ----
    {
        const float4* src = reinterpret_cast<const float4*>(w_out);
        #pragma unroll
        for (int r = 0; r < (NW * E / 4) / BLOCK; ++r) {
            int idx = tid + r * BLOCK;       // float4 index into [768][8]
            float4 v = src[idx];
            int e  = idx >> 1;               // two float4 per e-row
            int n0 = (idx & 1) * 4;
            wt_lds[n0 + 0][e] = v.x;
            wt_lds[n0 + 1][e] = v.y;
            wt_lds[n0 + 2][e] = v.z;
            wt_lds[n0 + 3][e] = v.w;
        }
    }
    float qp[NW];
    #pragma unroll
    for (int n = 0; n < NW; ++n) qp[n] = q_params[n];   // uniform -> scalar loads
    __syncthreads();

    const int wave = tid >> 6;
    const int lane = tid & 63;
    const int col  = lane * 4;   // element offset within a 256-elem chunk

    const int tokw = blockIdx.x * TOK_PER_BLOCK + wave * (TOK_PER_BLOCK / 4);

    for (int it = 0; it < 4; ++it) {
        const int t0 = tokw + it * 4;   // this wave's 4 tokens

        // ---- load x: 4 tokens x 3 float4 per lane (fully coalesced, 1 KB/inst) ----
        float4 xv[4][3];
        #pragma unroll
        for (int tt = 0; tt < 4; ++tt) {
            const float4* xp = reinterpret_cast<const float4*>(x + (size_t)(t0 + tt) * E);
            #pragma unroll
            for (int k = 0; k < 3; ++k)
                xv[tt][k] = xp[lane + k * 64];
        }

        // ---- per-lane partial dots: z[tt][n] (w_q LDS reads amortized over 4 tokens) ----
        float z[4][NW];
        #pragma unroll
        for (int n = 0; n < NW; ++n) {
            const float4 w0 = *reinterpret_cast<const float4*>(&wq_lds[n][col]);
            const float4 w1 = *reinterpret_cast<const float4*>(&wq_lds[n][col + 256]);
            const float4 w2 = *reinterpret_cast<const float4*>(&wq_lds[n][col + 512]);
            #pragma unroll
            for (int tt = 0; tt < 4; ++tt)
                z[tt][n] = dot12(xv[tt][0], xv[tt][1], xv[tt][2], w0, w1, w2);
        }

        // ---- wave reduce, cos, prefix products ----
        #pragma unroll
        for (int tt = 0; tt < 4; ++tt) {
            float c[NW];
            #pragma unroll
            for (int n = 0; n < NW; ++n) {
                float v = z[tt][n];
                #pragma unroll
                for (int m = 32; m >= 1; m >>= 1)
                    v += __shfl_xor(v, m, 64);
                c[n] = __cosf(v + qp[n]);
            }
            float pref = c[0];
            #pragma unroll
            for (int n = 1; n < NW; ++n) { pref *= c[n]; z[tt][n] = pref; }  // z_w = c0..cw
            float suf = c[1];
            #pragma unroll
            for (int n = 2; n < NW; ++n) suf *= c[n];
            z[tt][0] = suf;                                                  // z_0 = c1..c7
        }

        // ---- epilogue: out[t][e] = sum_n z[n] * w_out[e][n], w_out reads amortized 4x ----
        #pragma unroll
        for (int k = 0; k < 3; ++k) {
            float4 wv[NW];
            #pragma unroll
            for (int n = 0; n < NW; ++n)
                wv[n] = *reinterpret_cast<const float4*>(&wt_lds[n][k * 256 + col]);
            #pragma unroll
            for (int tt = 0; tt < 4; ++tt) {
                float ox = 0.f, oy = 0.f, oz = 0.f, ow = 0.f;
                #pragma unroll
                for (int n = 0; n < NW; ++n) {
                    ox += z[tt][n] * wv[n].x;
                    oy += z[tt][n] * wv[n].y;
                    oz += z[tt][n] * wv[n].z;
                    ow += z[tt][n] * wv[n].w;
                }
                float4 o; o.x = ox; o.y = oy; o.z = oz; o.w = ow;
                *reinterpret_cast<float4*>(out + (size_t)(t0 + tt) * E + k * 256 + col) = o;
            }
        }
    }
}

extern "C" void kernel_launch(void* const* d_in, const int* in_sizes, int n_in,
                              void* d_out, int out_size, void* d_ws, size_t ws_size,
                              hipStream_t stream) {
    const float* x        = (const float*)d_in[0];
    const float* w_q      = (const float*)d_in[1];
    const float* w_out    = (const float*)d_in[2];
    const float* q_params = (const float*)d_in[3];
    float* out = (float*)d_out;

    hipLaunchKernelGGL(mhaq_kernel, dim3(GRID), dim3(BLOCK), 0, stream,
                       x, w_q, w_out, q_params, out);
}

// Round 2
// 55.414 us; speedup vs baseline: 1.5700x; 1.5700x over previous
//
#include <hip/hip_runtime.h>
#include <math.h>

// MultiHeadAttentionQuantum: analytic collapse of the 8-qubit circuit.
//   angles[t][n] = dot(x[t], w_q[n]) + q_params[n]
//   c[n] = cos(angles[n])
//   z[0] = c1*...*c7 ; z[w] = c0*...*cw (w>=1)   (Heisenberg CNOT-ring push-through)
//   out[t][e] = sum_n z[n] * w_out[e][n]
//
// R1: latency-bound (occ 19%, VALU 13%, HBM 35%). Drop LDS staging (weights are
// coalesced + cache-resident anyway), grid 512->2048, 16 tokens/block one-shot,
// launch_bounds(256,4) for 4 waves/SIMD, nontemporal x loads / out stores.

using f32x4 = __attribute__((ext_vector_type(4))) float;

constexpr int E  = 768;
constexpr int NW = 8;
constexpr int BLOCK = 256;           // 4 waves
constexpr int TOK_PER_WAVE  = 4;
constexpr int TOK_PER_BLOCK = TOK_PER_WAVE * 4;        // 16
constexpr int GRID = (16 * 2048) / TOK_PER_BLOCK;      // 2048

__device__ __forceinline__ float dot12(const f32x4& a0, const f32x4& a1, const f32x4& a2,
                                       const f32x4& b0, const f32x4& b1, const f32x4& b2) {
    return a0.x*b0.x + a0.y*b0.y + a0.z*b0.z + a0.w*b0.w
         + a1.x*b1.x + a1.y*b1.y + a1.z*b1.z + a1.w*b1.w
         + a2.x*b2.x + a2.y*b2.y + a2.z*b2.z + a2.w*b2.w;
}

__global__ __launch_bounds__(BLOCK, 4)
void mhaq_kernel(const float* __restrict__ x,
                 const float* __restrict__ w_q,
                 const float* __restrict__ w_out,
                 const float* __restrict__ q_params,
                 float* __restrict__ out)
{
    const int tid  = threadIdx.x;
    const int wave = tid >> 6;
    const int lane = tid & 63;
    const int col  = lane * 4;                 // element offset within a 256-elem chunk

    const int t0 = blockIdx.x * TOK_PER_BLOCK + wave * TOK_PER_WAVE;

    float qp[NW];
    #pragma unroll
    for (int n = 0; n < NW; ++n) qp[n] = q_params[n];   // uniform -> s_load

    // ---- x loads: 4 tokens x 3 f32x4 per lane, coalesced 1KB/inst, nontemporal ----
    f32x4 xv[TOK_PER_WAVE][3];
    #pragma unroll
    for (int tt = 0; tt < TOK_PER_WAVE; ++tt) {
        const f32x4* xp = reinterpret_cast<const f32x4*>(x + (size_t)(t0 + tt) * E);
        #pragma unroll
        for (int k = 0; k < 3; ++k)
            xv[tt][k] = __builtin_nontemporal_load(xp + lane + k * 64);
    }

    // ---- per-lane partial dots (weights straight from L1/L2, coalesced) ----
    float z[TOK_PER_WAVE][NW];
    #pragma unroll
    for (int n = 0; n < NW; ++n) {
        const f32x4* wp = reinterpret_cast<const f32x4*>(w_q + n * E + col);
        const f32x4 w0 = wp[0];
        const f32x4 w1 = wp[64];
        const f32x4 w2 = wp[128];
        #pragma unroll
        for (int tt = 0; tt < TOK_PER_WAVE; ++tt)
            z[tt][n] = dot12(xv[tt][0], xv[tt][1], xv[tt][2], w0, w1, w2);
    }

    // ---- wave all-reduce (butterfly), cos, prefix products ----
    #pragma unroll
    for (int tt = 0; tt < TOK_PER_WAVE; ++tt) {
        float c[NW];
        #pragma unroll
        for (int n = 0; n < NW; ++n) {
            float v = z[tt][n];
            #pragma unroll
            for (int m = 32; m >= 1; m >>= 1)
                v += __shfl_xor(v, m, 64);
            c[n] = __cosf(v + qp[n]);
        }
        float pref = c[0];
        #pragma unroll
        for (int n = 1; n < NW; ++n) { pref *= c[n]; z[tt][n] = pref; }  // z_w = c0..cw
        float suf = c[1];
        #pragma unroll
        for (int n = 2; n < NW; ++n) suf *= c[n];
        z[tt][0] = suf;                                                  // z_0 = c1..c7
    }

    // ---- epilogue: out[t][e] = sum_n z[n] * w_out[e][n] ----
    #pragma unroll
    for (int k = 0; k < 3; ++k) {
        const int e0 = k * 256 + col;          // this lane's 4 output elements
        f32x4 wa[4], wb[4];                    // w_out rows e0..e0+3 (8 floats each)
        #pragma unroll
        for (int e = 0; e < 4; ++e) {
            const f32x4* wp = reinterpret_cast<const f32x4*>(w_out + (size_t)(e0 + e) * NW);
            wa[e] = wp[0];                     // n = 0..3
            wb[e] = wp[1];                     // n = 4..7
        }
        #pragma unroll
        for (int tt = 0; tt < TOK_PER_WAVE; ++tt) {
            f32x4 o;
            #pragma unroll
            for (int e = 0; e < 4; ++e) {
                float v = z[tt][0] * wa[e].x + z[tt][1] * wa[e].y
                        + z[tt][2] * wa[e].z + z[tt][3] * wa[e].w
                        + z[tt][4] * wb[e].x + z[tt][5] * wb[e].y
                        + z[tt][6] * wb[e].z + z[tt][7] * wb[e].w;
                if (e == 0) o.x = v; else if (e == 1) o.y = v;
                else if (e == 2) o.z = v; else o.w = v;
            }
            __builtin_nontemporal_store(
                o, reinterpret_cast<f32x4*>(out + (size_t)(t0 + tt) * E + e0));
        }
    }
}

extern "C" void kernel_launch(void* const* d_in, const int* in_sizes, int n_in,
                              void* d_out, int out_size, void* d_ws, size_t ws_size,
                              hipStream_t stream) {
    const float* x        = (const float*)d_in[0];
    const float* w_q      = (const float*)d_in[1];
    const float* w_out    = (const float*)d_in[2];
    const float* q_params = (const float*)d_in[3];
    float* out = (float*)d_out;

    hipLaunchKernelGGL(mhaq_kernel, dim3(GRID), dim3(BLOCK), 0, stream,
                       x, w_q, w_out, q_params, out);
}